// Round 4
// baseline (333.153 us; speedup 1.0000x reference)
//
#include <hip/hip_runtime.h>
#include <hip/hip_bf16.h>

#define NN 1024
#define IN_CH 128
#define EDGE_CH 32
#define OUT_CH 128

typedef __attribute__((ext_vector_type(8))) short bf16x8;
typedef __attribute__((ext_vector_type(4))) float f32x4;

// round-to-nearest-even float -> bf16
static __device__ __forceinline__ short f2bf(float f) {
    union { float f; unsigned u; } v; v.f = f;
    unsigned r = v.u + 0x7FFFu + ((v.u >> 16) & 1u);
    return (short)(r >> 16);
}

// ---------------------------------------------------------------------------
// Kernel A: PT[o][m] (bf16) = (node_mat @ node_weight)^T ; R = node_mat @ root
// ---------------------------------------------------------------------------
__global__ void node_gemm_kernel(const float* __restrict__ node_mat,
                                 const float* __restrict__ node_weight,
                                 const float* __restrict__ root,
                                 short* __restrict__ PT,
                                 float* __restrict__ R) {
    __shared__ float nm[2 * IN_CH];
    int tid = threadIdx.x;
    int n0 = blockIdx.x * 2;
    nm[tid] = node_mat[n0 * IN_CH + tid];
    __syncthreads();
    int o = tid & 127;
    int h = tid >> 7;
    const float* nr = &nm[h * IN_CH];
    float accp = 0.f, accr = 0.f;
#pragma unroll 8
    for (int c = 0; c < IN_CH; ++c) {
        float x = nr[c];
        accp += x * node_weight[c * OUT_CH + o];
        accr += x * root[c * OUT_CH + o];
    }
    R[(size_t)(n0 + h) * OUT_CH + o] = accr;
    PT[(size_t)o * NN + (n0 + h)] = f2bf(accp);
}

// ---------------------------------------------------------------------------
// Kernel B: out = adj @ P + R + bias.  NO atomics: grid 256, block owns an
// exclusive 16n x 32o tile, K=1024 split over the 4 waves, LDS reduce.
// A-frag: A[row=col][k=quad*8+j]; B-frag: B[k=quad*8+j][col]; D: row=quad*4+r.
// ---------------------------------------------------------------------------
__global__ void adjp_kernel(const float* __restrict__ adj,
                            const short* __restrict__ PT,
                            const float* __restrict__ R,
                            const float* __restrict__ bias,
                            float* __restrict__ out) {
    int nt = blockIdx.x >> 2;
    int ob = (blockIdx.x & 3) * 32;
    int tid = threadIdx.x;
    int wave = tid >> 6;
    int lane = tid & 63;
    int quad = lane >> 4;
    int col  = lane & 15;
    int n0 = nt * 16;

    f32x4 acc0 = {0.f, 0.f, 0.f, 0.f};
    f32x4 acc1 = {0.f, 0.f, 0.f, 0.f};
#pragma unroll 2
    for (int ks = 0; ks < 8; ++ks) {
        int k = wave * 256 + ks * 32 + quad * 8;
        const float* ap = adj + (size_t)(n0 + col) * NN + k;
        bf16x8 a;
#pragma unroll
        for (int j = 0; j < 8; ++j) a[j] = f2bf(ap[j]);
        bf16x8 b0 = *(const bf16x8*)(PT + (size_t)(ob + col) * NN + k);
        bf16x8 b1 = *(const bf16x8*)(PT + (size_t)(ob + 16 + col) * NN + k);
        acc0 = __builtin_amdgcn_mfma_f32_16x16x32_bf16(a, b0, acc0, 0, 0, 0);
        acc1 = __builtin_amdgcn_mfma_f32_16x16x32_bf16(a, b1, acc1, 0, 0, 0);
    }

    __shared__ float red[4][32][17];   // [wave][o_local][n_local], padded
#pragma unroll
    for (int r = 0; r < 4; ++r) {
        red[wave][col][quad * 4 + r]      = acc0[r];
        red[wave][16 + col][quad * 4 + r] = acc1[r];
    }
    __syncthreads();
    for (int i = tid; i < 512; i += 256) {
        int ol = i >> 4, nl = i & 15;
        float v = red[0][ol][nl] + red[1][ol][nl] + red[2][ol][nl] + red[3][ol][nl];
        int o = ob + ol, nr = n0 + nl;
        out[(size_t)nr * OUT_CH + o] = v + R[(size_t)nr * OUT_CH + o] + bias[o];
    }
}

// ---------------------------------------------------------------------------
// Kernel C (heavy, runs LAST): out[n,:] += e_compress[n,:]
//   G[b] = sum_m adj[n,m]*relu(sum_e ea[e,n,m]*L1[e,b]);  e_comp = G[:127]@L2
// One block (4 waves) per n. Wave owns 256 m as 8 chunks of 32 m.
// Software-pipelined register double-buffer: chunk c+1's 18 loads are issued
// BEFORE chunk c's compute, so the compiler's vmcnt wait only covers chunk c
// while c+1 streams. 8 per-lane base pointers -> each load is one
// global_load_dword with a small immediate offset.
// ---------------------------------------------------------------------------
__global__ void edge_out_kernel(const float* __restrict__ edge_adj,
                                const float* __restrict__ adj,
                                const float* __restrict__ L1,
                                const float* __restrict__ L2,
                                float* __restrict__ out) {
    int n = blockIdx.x;
    int tid = threadIdx.x;
    int wave = tid >> 6;
    int lane = tid & 63;
    int quad = lane >> 4;
    int col  = lane & 15;

    // constant A fragments: 8 b-tiles of L1^T [b=bt*16+col][e=quad*8+j]
    bf16x8 a_frag[8];
#pragma unroll
    for (int bt = 0; bt < 8; ++bt) {
        int b = bt * 16 + col;
#pragma unroll
        for (int j = 0; j < 8; ++j) {
            int e = quad * 8 + j;
            float v = (b < OUT_CH - 1) ? L1[e * (OUT_CH - 1) + b] : 0.0f;
            a_frag[bt][j] = f2bf(v);
        }
    }

    float g_acc[8][4];
#pragma unroll
    for (int bt = 0; bt < 8; ++bt)
#pragma unroll
        for (int r = 0; r < 4; ++r) g_acc[bt][r] = 0.0f;

    // per-lane base pointers: e = quad*8+j, m = wave*256 + col (+ imm offsets)
    const float* base[8];
#pragma unroll
    for (int j = 0; j < 8; ++j)
        base[j] = edge_adj + (size_t)(quad * 8 + j) * (size_t)(NN * NN)
                + (size_t)n * NN + wave * 256 + col;
    const float* abase = adj + (size_t)n * NN + wave * 256 + col;

    // register double buffers: 16 edge floats + 2 adj floats per chunk
    float eb[2][16];
    float av[2][2];

    // prologue: chunk 0 -> slot 0
#pragma unroll
    for (int s = 0; s < 2; ++s) av[0][s] = abase[s * 16];
#pragma unroll
    for (int j = 0; j < 8; ++j)
#pragma unroll
        for (int s = 0; s < 2; ++s) eb[0][j * 2 + s] = base[j][s * 16];

#pragma unroll
    for (int c = 0; c < 8; ++c) {
        int cur = c & 1, nxt = cur ^ 1;
        if (c < 7) {
            int off = (c + 1) * 32;
#pragma unroll
            for (int s = 0; s < 2; ++s) av[nxt][s] = abase[off + s * 16];
#pragma unroll
            for (int j = 0; j < 8; ++j)
#pragma unroll
                for (int s = 0; s < 2; ++s)
                    eb[nxt][j * 2 + s] = base[j][off + s * 16];
        }
#pragma unroll
        for (int s = 0; s < 2; ++s) {
            bf16x8 bf;
#pragma unroll
            for (int j = 0; j < 8; ++j) bf[j] = f2bf(eb[cur][j * 2 + s]);
            float a = av[cur][s];
#pragma unroll
            for (int bt = 0; bt < 8; ++bt) {
                f32x4 d = __builtin_amdgcn_mfma_f32_16x16x32_bf16(
                    a_frag[bt], bf, (f32x4){0.f, 0.f, 0.f, 0.f}, 0, 0, 0);
#pragma unroll
                for (int r = 0; r < 4; ++r)
                    g_acc[bt][r] += fmaxf(d[r], 0.0f) * a;
            }
        }
    }

    // reduce over the 16 column-lanes of each quad
#pragma unroll
    for (int bt = 0; bt < 8; ++bt)
#pragma unroll
        for (int r = 0; r < 4; ++r) {
            float v = g_acc[bt][r];
            v += __shfl_xor(v, 1);
            v += __shfl_xor(v, 2);
            v += __shfl_xor(v, 4);
            v += __shfl_xor(v, 8);
            g_acc[bt][r] = v;
        }

    __shared__ float gred[4][OUT_CH];
    __shared__ float gs[OUT_CH];
    __shared__ float part[2][OUT_CH];
    if (col == 0) {
#pragma unroll
        for (int bt = 0; bt < 8; ++bt)
#pragma unroll
            for (int r = 0; r < 4; ++r)
                gred[wave][bt * 16 + quad * 4 + r] = g_acc[bt][r];
    }
    __syncthreads();
    if (tid < OUT_CH)
        gs[tid] = gred[0][tid] + gred[1][tid] + gred[2][tid] + gred[3][tid];
    __syncthreads();

    // out[n,o] += sum_{b<127} gs[b]*L2[b,o]
    int o = tid & 127;
    int hf = tid >> 7;
    float acc = 0.f;
    int blo = hf * 64, bhi = hf ? 127 : 64;
#pragma unroll 8
    for (int b = blo; b < bhi; ++b)
        acc += gs[b] * L2[b * OUT_CH + o];
    part[hf][o] = acc;
    __syncthreads();
    if (tid < 128)
        out[(size_t)n * OUT_CH + tid] += part[0][tid] + part[1][tid];
}

extern "C" void kernel_launch(void* const* d_in, const int* in_sizes, int n_in,
                              void* d_out, int out_size, void* d_ws, size_t ws_size,
                              hipStream_t stream) {
    const float* node_mat    = (const float*)d_in[0];
    const float* adj         = (const float*)d_in[1];
    const float* edge_adj    = (const float*)d_in[2];
    const float* node_weight = (const float*)d_in[3];
    const float* edge_lay_1  = (const float*)d_in[4];
    const float* edge_lay_2  = (const float*)d_in[5];
    const float* root        = (const float*)d_in[6];
    const float* bias        = (const float*)d_in[7];
    float* out = (float*)d_out;

    short* PT = (short*)d_ws;                                         // 256 KB
    float* R  = (float*)((char*)d_ws + OUT_CH * NN * sizeof(short));  // 512 KB

    node_gemm_kernel<<<NN / 2, 256, 0, stream>>>(node_mat, node_weight, root, PT, R);
    adjp_kernel<<<256, 256, 0, stream>>>(adj, PT, R, bias, out);
    edge_out_kernel<<<NN, 256, 0, stream>>>(edge_adj, adj, edge_lay_1, edge_lay_2, out);
}